// Round 6
// baseline (103.680 us; speedup 1.0000x reference)
//
#include <hip/hip_runtime.h>

typedef short bf16x8 __attribute__((ext_vector_type(8)));
typedef float f32x4 __attribute__((ext_vector_type(4)));

__device__ __forceinline__ unsigned short f2bf(float f) {
  union { float f; unsigned u; } c; c.f = f;
  unsigned u = c.u;
  u += 0x7FFFu + ((u >> 16) & 1u);   // RNE
  return (unsigned short)(u >> 16);
}
__device__ __forceinline__ float bf2f(unsigned short h) {
  union { unsigned u; float f; } c; c.u = ((unsigned)h) << 16;
  return c.f;
}
// truncation split: hi = trunc-to-bf16(v), lo = RNE(v - hi)
__device__ __forceinline__ void split2(float v, unsigned short& hi, unsigned short& lo) {
  union { float f; unsigned u; } c; c.f = v;
  unsigned uh = c.u & 0xFFFF0000u;
  hi = (unsigned short)(uh >> 16);
  union { unsigned u; float f; } d; d.u = uh;
  lo = f2bf(v - d.f);
}
__device__ __forceinline__ void gload16(const void* g, void* l) {
  __builtin_amdgcn_global_load_lds((const __attribute__((address_space(1))) void*)g,
                                   (__attribute__((address_space(3))) void*)l, 16, 0, 0);
}
__device__ __forceinline__ float sigm(float x) { return 1.0f / (1.0f + __expf(-x)); }
__device__ __forceinline__ float tanha(float x) { return 1.0f - 2.0f / (1.0f + __expf(2.0f * x)); }

// Abuf fragment layout: ushort index for (row 0..8191, col 0..1279)
// 1 KiB frag per (rowblk, cc, ks); lane = ((col>>3)&3)*16 + (row&15); e = col&7
__device__ __forceinline__ int fragIdx(int row, int col) {
  int rowblk = row >> 4;
  int cc = col >> 6;
  int ks = (col >> 5) & 1;
  int ln = (((col >> 3) & 3) << 4) | (row & 15);
  int e = col & 7;
  return (((rowblk * 20 + cc) * 2 + ks) << 9) + ln * 8 + e;
}

// ---------------- merged setup kernel ----------------
// [0, 262144): Wt[n][k] = W[k][n]                       (256x1024 bf16)
// [262144, 458752): Bg[g][n][k]                         (4x192x256 bf16)
// [458752, 2621440): Btp[j][kt][c2][q][c16][k2]         (4x11x16x3x16x64 bf16)
__global__ __launch_bounds__(256) void s123(
    const float* __restrict__ W,
    const float* __restrict__ U, const float* __restrict__ UU,
    const float* __restrict__ UUU, const float* __restrict__ UUUU,
    const float* __restrict__ W1, const float* __restrict__ W2, const float* __restrict__ W3,
    const float* __restrict__ A1, const float* __restrict__ A2, const float* __restrict__ A3,
    const float* __restrict__ B1, const float* __restrict__ B2, const float* __restrict__ B3,
    const float* __restrict__ C1, const float* __restrict__ C2, const float* __restrict__ C3,
    const float* __restrict__ D1, const float* __restrict__ D2, const float* __restrict__ D3,
    unsigned short* __restrict__ Wt, unsigned short* __restrict__ Bg,
    unsigned short* __restrict__ Btp) {
  int gidx = blockIdx.x * 256 + threadIdx.x;
  if (gidx < 262144) {
    int idx = gidx;
    int n = idx >> 10, k = idx & 1023;
    Wt[idx] = f2bf(W[k * 256 + n]);
  } else if (gidx < 458752) {
    int idx = gidx - 262144;
    int g = idx / 49152;
    int rem = idx - g * 49152;
    int n = rem >> 8, k = rem & 255;
    int jj = 0, rr = n;
#pragma unroll
    for (int s = 0; s < 3; ++s) {
      int w = (((g - jj) & 3) < 2) ? 64 : 32;
      if (rr >= w) { rr -= w; ++jj; }
    }
    int v = (g - jj) & 3;
    int rv = (v < 2) ? 64 : 32;
    const float* M = (v == 0) ? U : (v == 1) ? UU : (v == 2) ? UUU : UUUU;
    Bg[idx] = f2bf(M[(jj * 256 + k) * rv + rr]);
  } else {
    int idx = gidx - 458752;
    int j  = idx / 540672;            // 11*16*3*16*64
    int r1 = idx - j * 540672;
    int kt = r1 / 49152;              // 16*3*16*64
    int r2 = r1 - kt * 49152;
    int c2 = r2 / 3072;               // 3*16*64
    int r3 = r2 - c2 * 3072;
    int q  = r3 >> 10;                // /1024
    int r4 = r3 & 1023;
    int c16 = r4 >> 6;
    int k2  = r4 & 63;
    int c = c2 * 16 + c16;
    float val;
    if (kt < 8) {
      int kk = (kt * 64 + k2) & 255;
      const float* Wp = (q == 0) ? W1 : (q == 1) ? W2 : W3;
      val = Wp[kk * 1024 + j * 256 + c];
    } else {
      int kT = (kt - 8) * 64 + k2;
      int v, r, rv;
      if (kT < 64)       { v = 0; r = kT;       rv = 64; }
      else if (kT < 128) { v = 1; r = kT - 64;  rv = 64; }
      else if (kT < 160) { v = 2; r = kT - 128; rv = 32; }
      else               { v = 3; r = kT - 160; rv = 32; }
      const float* M;
      if (v == 0)      M = (q == 0) ? A1 : (q == 1) ? A2 : A3;
      else if (v == 1) M = (q == 0) ? B1 : (q == 1) ? B2 : B3;
      else if (v == 2) M = (q == 0) ? C1 : (q == 1) ? C2 : C3;
      else             M = (q == 0) ? D1 : (q == 1) ? D2 : D3;
      val = M[(j * rv + r) * 256 + c];
    }
    Btp[idx] = f2bf(val);
  }
}

// ---------------- G1: xw = x @ W, hi/lo 2-pass, BM=32 BN=128, counted-vmcnt pipeline
// LDS: Ahi @ buf*4096, Alo @ 8192+buf*4096, B @ 16384+buf*16384 (48 KiB)
__global__ __launch_bounds__(256) void g1_xw(const float* __restrict__ x,
                                             const unsigned short* __restrict__ Wt,
                                             unsigned short* __restrict__ Abuf) {
  __shared__ char lds[49152];
  const int tid = threadIdx.x, lane = tid & 63, wid = tid >> 6;
  const int mb = blockIdx.x, nb = blockIdx.y;
  const int wn = wid;
  f32x4 acc[2][2] = {};
  float4 xr[2];
  const int r0 = tid >> 4, f4c = tid & 15;
  const float* xbase = x + (size_t)(mb * 32) * 1024 + f4c * 4;

  auto loadX = [&](int kt) {
#pragma unroll
    for (int q = 0; q < 2; ++q)
      xr[q] = *(const float4*)(xbase + (size_t)(q * 16 + r0) * 1024 + kt * 64);
  };
  auto writeA = [&](int buf) {
#pragma unroll
    for (int q = 0; q < 2; ++q) {
      int row = q * 16 + r0;
      float4 v = xr[q];
      unsigned short h0, h1, h2, h3, l0, l1, l2, l3;
      split2(v.x, h0, l0); split2(v.y, h1, l1);
      split2(v.z, h2, l2); split2(v.w, h3, l3);
      int ba = row * 128 + ((f4c * 8) ^ ((row & 7) << 4));
      *(uint2*)(lds + buf * 4096 + ba) =
          make_uint2(((unsigned)h1 << 16) | h0, ((unsigned)h3 << 16) | h2);
      *(uint2*)(lds + 8192 + buf * 4096 + ba) =
          make_uint2(((unsigned)l1 << 16) | l0, ((unsigned)l3 << 16) | l2);
    }
  };
  auto stageB = [&](int kt, int buf) {
#pragma unroll
    for (int it = 0; it < 4; ++it) {
      int nloc = it * 32 + wid * 8 + (lane >> 3);
      const char* src = (const char*)Wt + (size_t)(nb * 128 + nloc) * 2048 + kt * 128
                        + (((lane & 7) * 16) ^ ((nloc & 7) << 4));
      gload16(src, lds + 16384 + buf * 16384 + (it * 32 + wid * 8) * 128);
    }
  };

  loadX(0); stageB(0, 0); writeA(0);
  __syncthreads();
#pragma unroll 2
  for (int kt = 0; kt < 16; ++kt) {
    int buf = kt & 1;
    if (kt < 15) {
      loadX(kt + 1); stageB(kt + 1, buf ^ 1);
      asm volatile("s_waitcnt vmcnt(6)" ::: "memory");
    } else {
      asm volatile("s_waitcnt vmcnt(0)" ::: "memory");
    }
    __builtin_amdgcn_s_barrier();
    __builtin_amdgcn_sched_barrier(0);
    const char* hA = lds + buf * 4096;
    const char* lA = lds + 8192 + buf * 4096;
    const char* bB = lds + 16384 + buf * 16384;
#pragma unroll
    for (int ks = 0; ks < 2; ++ks) {
      bf16x8 ah[2], al[2], b[2];
#pragma unroll
      for (int mf = 0; mf < 2; ++mf) {
        int mloc = mf * 16 + (lane & 15);
        int ka = (ks * 64 + (lane >> 4) * 16) ^ ((mloc & 7) << 4);
        ah[mf] = *(const bf16x8*)(hA + mloc * 128 + ka);
        al[mf] = *(const bf16x8*)(lA + mloc * 128 + ka);
      }
#pragma unroll
      for (int nf = 0; nf < 2; ++nf) {
        int nloc = wn * 32 + nf * 16 + (lane & 15);
        int kb = (ks * 64 + (lane >> 4) * 16) ^ ((nloc & 7) << 4);
        b[nf] = *(const bf16x8*)(bB + nloc * 128 + kb);
      }
#pragma unroll
      for (int mf = 0; mf < 2; ++mf)
#pragma unroll
        for (int nf = 0; nf < 2; ++nf) {
          acc[mf][nf] = __builtin_amdgcn_mfma_f32_16x16x32_bf16(ah[mf], b[nf], acc[mf][nf], 0, 0, 0);
          acc[mf][nf] = __builtin_amdgcn_mfma_f32_16x16x32_bf16(al[mf], b[nf], acc[mf][nf], 0, 0, 0);
        }
    }
    if (kt < 15) writeA(buf ^ 1);
    __builtin_amdgcn_sched_barrier(0);
    asm volatile("s_waitcnt lgkmcnt(0)" ::: "memory");
    __builtin_amdgcn_s_barrier();
  }
#pragma unroll
  for (int mf = 0; mf < 2; ++mf)
#pragma unroll
    for (int nf = 0; nf < 2; ++nf)
#pragma unroll
      for (int r = 0; r < 4; ++r) {
        int row = mb * 32 + mf * 16 + (lane >> 4) * 4 + r;
        int col = nb * 128 + wn * 32 + nf * 16 + (lane & 15);
        float val = acc[mf][nf][r];
        unsigned short hi, lo;
        split2(val, hi, lo);
        Abuf[fragIdx(row, col)] = hi;
        Abuf[fragIdx(row, col + 256)] = lo;
      }
}

// ---------------- G2: zero-skip T = h_g @ Bg, BM=64, N=192, K=256, 2-phase
__global__ __launch_bounds__(256) void g2_t(const float* __restrict__ h,
                                            const unsigned short* __restrict__ Bg,
                                            unsigned short* __restrict__ Abuf) {
  __shared__ char lds[65536];
  const int tid = threadIdx.x, lane = tid & 63, wid = tid >> 6;
  const int mb = blockIdx.x, g = blockIdx.y;
  const int wm = wid >> 1, wn = wid & 1;
  f32x4 acc[2][6] = {};
  float4 hr[4];
  const int r0 = tid >> 4, f4c = tid & 15;
  const float* hbase = h + (size_t)(mb * 64) * 1024 + g * 256 + f4c * 4;

  auto loadH = [&](int kt) {
#pragma unroll
    for (int q = 0; q < 4; ++q)
      hr[q] = *(const float4*)(hbase + (size_t)(q * 16 + r0) * 1024 + kt * 64);
  };
  auto writeA = [&](int buf) {
#pragma unroll
    for (int q = 0; q < 4; ++q) {
      int row = q * 16 + r0;
      float4 v = hr[q];
      int ba = row * 128 + ((f4c * 8) ^ ((row & 7) << 4));
      *(uint2*)(lds + buf * 8192 + ba) =
          make_uint2(((unsigned)f2bf(v.y) << 16) | f2bf(v.x),
                     ((unsigned)f2bf(v.w) << 16) | f2bf(v.z));
    }
  };
  auto stageB = [&](int kt, int buf) {
#pragma unroll
    for (int it = 0; it < 6; ++it) {
      int nloc = it * 32 + wid * 8 + (lane >> 3);
      const char* src = (const char*)Bg + (size_t)(g * 192 + nloc) * 512 + kt * 128
                        + (((lane & 7) * 16) ^ ((nloc & 7) << 4));
      gload16(src, lds + 16384 + buf * 24576 + (it * 32 + wid * 8) * 128);
    }
  };

  loadH(0); stageB(0, 0); writeA(0);
  __syncthreads();
#pragma unroll
  for (int kt = 0; kt < 4; ++kt) {
    int buf = kt & 1;
    if (kt < 3) { loadH(kt + 1); stageB(kt + 1, buf ^ 1); }
    const char* cA = lds + buf * 8192;
    const char* cB = lds + 16384 + buf * 24576;
#pragma unroll
    for (int ks = 0; ks < 2; ++ks) {
      bf16x8 a[2], b[6];
#pragma unroll
      for (int mf = 0; mf < 2; ++mf) {
        int mloc = wm * 32 + mf * 16 + (lane & 15);
        int ka = (ks * 64 + (lane >> 4) * 16) ^ ((mloc & 7) << 4);
        a[mf] = *(const bf16x8*)(cA + mloc * 128 + ka);
      }
#pragma unroll
      for (int nf = 0; nf < 6; ++nf) {
        int nloc = wn * 96 + nf * 16 + (lane & 15);
        int kb = (ks * 64 + (lane >> 4) * 16) ^ ((nloc & 7) << 4);
        b[nf] = *(const bf16x8*)(cB + nloc * 128 + kb);
      }
#pragma unroll
      for (int mf = 0; mf < 2; ++mf)
#pragma unroll
        for (int nf = 0; nf < 6; ++nf)
          acc[mf][nf] = __builtin_amdgcn_mfma_f32_16x16x32_bf16(a[mf], b[nf], acc[mf][nf], 0, 0, 0);
    }
    if (kt < 3) writeA(buf ^ 1);
    __syncthreads();
  }
#pragma unroll
  for (int mf = 0; mf < 2; ++mf)
#pragma unroll
    for (int nf = 0; nf < 6; ++nf) {
      int n = wn * 96 + nf * 16 + (lane & 15);
      int jj = 0, rr = n;
#pragma unroll
      for (int s = 0; s < 3; ++s) {
        int w = (((g - jj) & 3) < 2) ? 64 : 32;
        if (rr >= w) { rr -= w; ++jj; }
      }
      int v = (g - jj) & 3;
      int offv = (v < 2) ? (v << 6) : (64 + (v << 5));
      int col = 512 + jj * 192 + offv + rr;
#pragma unroll
      for (int r = 0; r < 4; ++r) {
        int row = mb * 64 + wm * 32 + mf * 16 + (lane >> 4) * 4 + r;
        Abuf[fragIdx(row, col)] = f2bf(acc[mf][nf][r]);
      }
    }
}

// ---------------- G3: fused GEMM + GRU epilogue
// A: global->VGPR fragment loads (dbuf, 1 kt ahead); B: LDS 2x12KB; counted vmcnt(11)
__global__ __launch_bounds__(256) void g3_main(const unsigned short* __restrict__ Abuf,
                                               const unsigned short* __restrict__ Btp,
                                               const float* __restrict__ h,
                                               const float* __restrict__ bias_r,
                                               const float* __restrict__ bias_g,
                                               const float* __restrict__ bias_u,
                                               float* __restrict__ out) {
  __shared__ char lds[24576];
  const int tid = threadIdx.x, lane = tid & 63, wid = tid >> 6;
  const int mb = blockIdx.x, nb = blockIdx.y, j = blockIdx.z;
  const int wm = wid >> 1, wn = wid & 1;
  f32x4 acc[4][4] = {};

  const char* AbufB = (const char*)Abuf + (size_t)(mb * 8 + wm * 4) * 40960 + lane * 16;
  const char* BtpJ  = (const char*)Btp + (size_t)j * 1081344;
  int thrB[3], dstB[3];
#pragma unroll
  for (int it = 0; it < 3; ++it) {
    int row = it * 32 + wid * 8 + (lane >> 3);
    thrB[it] = row * 128 + (((lane & 7) * 16) ^ ((row & 7) << 4));
    dstB[it] = (it * 32 + wid * 8) * 128;
  }
  const char* pB[3][2];
#pragma unroll
  for (int q = 0; q < 3; ++q) {
    int nloc = wn * 48 + q * 16 + (lane & 15);
#pragma unroll
    for (int ks = 0; ks < 2; ++ks)
      pB[q][ks] = lds + nloc * 128 + ((ks * 64 + (lane >> 4) * 16) ^ ((nloc & 7) << 4));
  }

  auto stageB = [&](int kt, int buf) {
    const char* bsrc = BtpJ + (size_t)(kt * 16 + nb * 2) * 6144;
#pragma unroll
    for (int it = 0; it < 3; ++it)
      gload16(bsrc + thrB[it], lds + buf * 12288 + dstB[it]);
  };
  bf16x8 aF[2][8];
  auto loadA = [&](int kt, int slot) {
    int cc = (kt < 8) ? kt : (8 + j * 3 + (kt - 8));
#pragma unroll
    for (int mf = 0; mf < 4; ++mf)
#pragma unroll
      for (int ks = 0; ks < 2; ++ks)
        aF[slot][mf * 2 + ks] =
            *(const bf16x8*)(AbufB + (size_t)mf * 40960 + cc * 2048 + ks * 1024);
  };

  // prologue: B(0) + A(0) in flight (11 vmem ops)
  stageB(0, 0);
  __builtin_amdgcn_sched_barrier(0);
  loadA(0, 0);
  __builtin_amdgcn_sched_barrier(0);

#pragma unroll
  for (int kt = 0; kt < 11; ++kt) {
    const int cur = kt & 1;
    if (kt < 10) {
      stageB(kt + 1, cur ^ 1);
      __builtin_amdgcn_sched_barrier(0);
      loadA(kt + 1, cur ^ 1);
      __builtin_amdgcn_sched_barrier(0);
      asm volatile("s_waitcnt vmcnt(11)" ::: "memory");
    } else {
      asm volatile("s_waitcnt vmcnt(0)" ::: "memory");
    }
    __builtin_amdgcn_s_barrier();
    __builtin_amdgcn_sched_barrier(0);
    __builtin_amdgcn_s_setprio(1);
#pragma unroll
    for (int ks = 0; ks < 2; ++ks) {
#pragma unroll
      for (int q = 0; q < 3; ++q) {
        int p = (kt < 8) ? q : ((q == 2) ? 3 : q);
        bf16x8 b = *(const bf16x8*)(pB[q][ks] + cur * 12288);
#pragma unroll
        for (int mf = 0; mf < 4; ++mf)
          acc[mf][p] = __builtin_amdgcn_mfma_f32_16x16x32_bf16(aF[cur][mf * 2 + ks], b,
                                                               acc[mf][p], 0, 0, 0);
      }
    }
    __builtin_amdgcn_s_setprio(0);
    __builtin_amdgcn_sched_barrier(0);
    asm volatile("s_waitcnt lgkmcnt(0)" ::: "memory");
    __builtin_amdgcn_s_barrier();
  }
  // fused GRU epilogue
  int cg = j * 256 + nb * 32 + wn * 16 + (lane & 15);
  float br = bias_r[cg], bg = bias_g[cg], bu = bias_u[cg];
#pragma unroll
  for (int mf = 0; mf < 4; ++mf)
#pragma unroll
    for (int r = 0; r < 4; ++r) {
      int row = mb * 128 + wm * 64 + mf * 16 + (lane >> 4) * 4 + r;
      float p0 = acc[mf][0][r], p1 = acc[mf][1][r];
      float p2 = acc[mf][2][r], p3 = acc[mf][3][r];
      float rr = sigm(p0 + br);
      float zz = sigm(p1 + bg);
      float ct = tanha(p2 + rr * p3 + bu);
      float hv = h[(size_t)row * 1024 + cg];
      out[(size_t)row * 1024 + cg] = zz * hv + (1.0f - zz) * ct;
    }
}

extern "C" void kernel_launch(void* const* d_in, const int* in_sizes, int n_in,
                              void* d_out, int out_size, void* d_ws, size_t ws_size,
                              hipStream_t stream) {
  const float* x   = (const float*)d_in[0];
  const float* h   = (const float*)d_in[1];
  const float* W   = (const float*)d_in[2];
  const float* W1  = (const float*)d_in[3];
  const float* W2  = (const float*)d_in[4];
  const float* W3  = (const float*)d_in[5];
  const float* U   = (const float*)d_in[6];
  const float* U1  = (const float*)d_in[7];
  const float* U2  = (const float*)d_in[8];
  const float* U3  = (const float*)d_in[9];
  const float* UU   = (const float*)d_in[10];
  const float* UU1  = (const float*)d_in[11];
  const float* UU2  = (const float*)d_in[12];
  const float* UU3  = (const float*)d_in[13];
  const float* UUU   = (const float*)d_in[14];
  const float* UUU1  = (const float*)d_in[15];
  const float* UUU2  = (const float*)d_in[16];
  const float* UUU3  = (const float*)d_in[17];
  const float* UUUU   = (const float*)d_in[18];
  const float* UUUU1  = (const float*)d_in[19];
  const float* UUUU2  = (const float*)d_in[20];
  const float* UUUU3  = (const float*)d_in[21];
  const float* bias_r = (const float*)d_in[22];
  const float* bias_g = (const float*)d_in[23];
  const float* bias_u = (const float*)d_in[24];

  char* ws = (char*)d_ws;
  unsigned short* Abuf = (unsigned short*)(ws);              // 8192x1280 bf16, fragment-ordered
  unsigned short* Wt   = (unsigned short*)(ws + 20971520);   // 256x1024 bf16
  unsigned short* Bg   = (unsigned short*)(ws + 21495808);   // 4x192x256 bf16
  unsigned short* Btp  = (unsigned short*)(ws + 21889024);   // 4x11x16x48x64 bf16
  float* out = (float*)d_out;

  s123<<<10240, 256, 0, stream>>>(W, U, UU, UUU, UUUU,
                                  W1, W2, W3, U1, U2, U3, UU1, UU2, UU3,
                                  UUU1, UUU2, UUU3, UUUU1, UUUU2, UUUU3,
                                  Wt, Bg, Btp);
  g1_xw<<<dim3(256, 2), 256, 0, stream>>>(x, Wt, Abuf);
  g2_t<<<dim3(128, 4), 256, 0, stream>>>(h, Bg, Abuf);
  g3_main<<<dim3(64, 8, 4), 256, 0, stream>>>(Abuf, Btp, h, bias_r, bias_g, bias_u, out);
}

// Round 7
// 93.026 us; speedup vs baseline: 1.1145x; 1.1145x over previous
//
#include <hip/hip_runtime.h>

typedef short bf16x8 __attribute__((ext_vector_type(8)));
typedef float f32x4 __attribute__((ext_vector_type(4)));

__device__ __forceinline__ unsigned short f2bf(float f) {
  union { float f; unsigned u; } c; c.f = f;
  unsigned u = c.u;
  u += 0x7FFFu + ((u >> 16) & 1u);   // RNE
  return (unsigned short)(u >> 16);
}
__device__ __forceinline__ float bf2f(unsigned short h) {
  union { unsigned u; float f; } c; c.u = ((unsigned)h) << 16;
  return c.f;
}
// truncation split: hi = trunc-to-bf16(v), lo = RNE(v - hi)
__device__ __forceinline__ void split2(float v, unsigned short& hi, unsigned short& lo) {
  union { float f; unsigned u; } c; c.f = v;
  unsigned uh = c.u & 0xFFFF0000u;
  hi = (unsigned short)(uh >> 16);
  union { unsigned u; float f; } d; d.u = uh;
  lo = f2bf(v - d.f);
}
__device__ __forceinline__ void gload16(const void* g, void* l) {
  __builtin_amdgcn_global_load_lds((const __attribute__((address_space(1))) void*)g,
                                   (__attribute__((address_space(3))) void*)l, 16, 0, 0);
}
__device__ __forceinline__ float sigm(float x) { return 1.0f / (1.0f + __expf(-x)); }
__device__ __forceinline__ float tanha(float x) { return 1.0f - 2.0f / (1.0f + __expf(2.0f * x)); }

// ---------------- merged setup kernel ----------------
// [0, 262144): Wt[n][k] = W[k][n]                       (256x1024 bf16)
// [262144, 458752): Bg[g][n][k]                         (4x192x256 bf16)
// [458752, 2621440): Btp[j][kt][c2][q][c16][k2]         (4x11x16x3x16x64 bf16)
__global__ __launch_bounds__(256) void s123(
    const float* __restrict__ W,
    const float* __restrict__ U, const float* __restrict__ UU,
    const float* __restrict__ UUU, const float* __restrict__ UUUU,
    const float* __restrict__ W1, const float* __restrict__ W2, const float* __restrict__ W3,
    const float* __restrict__ A1, const float* __restrict__ A2, const float* __restrict__ A3,
    const float* __restrict__ B1, const float* __restrict__ B2, const float* __restrict__ B3,
    const float* __restrict__ C1, const float* __restrict__ C2, const float* __restrict__ C3,
    const float* __restrict__ D1, const float* __restrict__ D2, const float* __restrict__ D3,
    unsigned short* __restrict__ Wt, unsigned short* __restrict__ Bg,
    unsigned short* __restrict__ Btp) {
  int gidx = blockIdx.x * 256 + threadIdx.x;
  if (gidx < 262144) {
    int idx = gidx;
    int n = idx >> 10, k = idx & 1023;
    Wt[idx] = f2bf(W[k * 256 + n]);
  } else if (gidx < 458752) {
    int idx = gidx - 262144;
    int g = idx / 49152;
    int rem = idx - g * 49152;
    int n = rem >> 8, k = rem & 255;
    int jj = 0, rr = n;
#pragma unroll
    for (int s = 0; s < 3; ++s) {
      int w = (((g - jj) & 3) < 2) ? 64 : 32;
      if (rr >= w) { rr -= w; ++jj; }
    }
    int v = (g - jj) & 3;
    int rv = (v < 2) ? 64 : 32;
    const float* M = (v == 0) ? U : (v == 1) ? UU : (v == 2) ? UUU : UUUU;
    Bg[idx] = f2bf(M[(jj * 256 + k) * rv + rr]);
  } else {
    int idx = gidx - 458752;
    int j  = idx / 540672;            // 11*16*3*16*64
    int r1 = idx - j * 540672;
    int kt = r1 / 49152;              // 16*3*16*64
    int r2 = r1 - kt * 49152;
    int c2 = r2 / 3072;               // 3*16*64
    int r3 = r2 - c2 * 3072;
    int q  = r3 >> 10;                // /1024
    int r4 = r3 & 1023;
    int c16 = r4 >> 6;
    int k2  = r4 & 63;
    int c = c2 * 16 + c16;
    float val;
    if (kt < 8) {
      int kk = (kt * 64 + k2) & 255;
      const float* Wp = (q == 0) ? W1 : (q == 1) ? W2 : W3;
      val = Wp[kk * 1024 + j * 256 + c];
    } else {
      int kT = (kt - 8) * 64 + k2;
      int v, r, rv;
      if (kT < 64)       { v = 0; r = kT;       rv = 64; }
      else if (kT < 128) { v = 1; r = kT - 64;  rv = 64; }
      else if (kT < 160) { v = 2; r = kT - 128; rv = 32; }
      else               { v = 3; r = kT - 160; rv = 32; }
      const float* M;
      if (v == 0)      M = (q == 0) ? A1 : (q == 1) ? A2 : A3;
      else if (v == 1) M = (q == 0) ? B1 : (q == 1) ? B2 : B3;
      else if (v == 2) M = (q == 0) ? C1 : (q == 1) ? C2 : C3;
      else             M = (q == 0) ? D1 : (q == 1) ? D2 : D3;
      val = M[(j * rv + r) * 256 + c];
    }
    Btp[idx] = f2bf(val);
  }
}

// ---------------- G1: xw = x @ W, hi/lo 2-pass, BM=32 BN=128, counted-vmcnt pipeline
// LDS: Ahi @ buf*4096, Alo @ 8192+buf*4096, B @ 16384+buf*16384 (48 KiB)
__global__ __launch_bounds__(256) void g1_xw(const float* __restrict__ x,
                                             const unsigned short* __restrict__ Wt,
                                             unsigned short* __restrict__ Abuf) {
  __shared__ char lds[49152];
  const int tid = threadIdx.x, lane = tid & 63, wid = tid >> 6;
  const int mb = blockIdx.x, nb = blockIdx.y;
  const int wn = wid;
  f32x4 acc[2][2] = {};
  float4 xr[2];
  const int r0 = tid >> 4, f4c = tid & 15;
  const float* xbase = x + (size_t)(mb * 32) * 1024 + f4c * 4;

  auto loadX = [&](int kt) {
#pragma unroll
    for (int q = 0; q < 2; ++q)
      xr[q] = *(const float4*)(xbase + (size_t)(q * 16 + r0) * 1024 + kt * 64);
  };
  auto writeA = [&](int buf) {
#pragma unroll
    for (int q = 0; q < 2; ++q) {
      int row = q * 16 + r0;
      float4 v = xr[q];
      unsigned short h0, h1, h2, h3, l0, l1, l2, l3;
      split2(v.x, h0, l0); split2(v.y, h1, l1);
      split2(v.z, h2, l2); split2(v.w, h3, l3);
      int ba = row * 128 + ((f4c * 8) ^ ((row & 7) << 4));
      *(uint2*)(lds + buf * 4096 + ba) =
          make_uint2(((unsigned)h1 << 16) | h0, ((unsigned)h3 << 16) | h2);
      *(uint2*)(lds + 8192 + buf * 4096 + ba) =
          make_uint2(((unsigned)l1 << 16) | l0, ((unsigned)l3 << 16) | l2);
    }
  };
  auto stageB = [&](int kt, int buf) {
#pragma unroll
    for (int it = 0; it < 4; ++it) {
      int nloc = it * 32 + wid * 8 + (lane >> 3);
      const char* src = (const char*)Wt + (size_t)(nb * 128 + nloc) * 2048 + kt * 128
                        + (((lane & 7) * 16) ^ ((nloc & 7) << 4));
      gload16(src, lds + 16384 + buf * 16384 + (it * 32 + wid * 8) * 128);
    }
  };

  loadX(0); stageB(0, 0); writeA(0);
  __syncthreads();
#pragma unroll 2
  for (int kt = 0; kt < 16; ++kt) {
    int buf = kt & 1;
    if (kt < 15) {
      loadX(kt + 1); stageB(kt + 1, buf ^ 1);
      asm volatile("s_waitcnt vmcnt(6)" ::: "memory");
    } else {
      asm volatile("s_waitcnt vmcnt(0)" ::: "memory");
    }
    __builtin_amdgcn_s_barrier();
    __builtin_amdgcn_sched_barrier(0);
    const char* hA = lds + buf * 4096;
    const char* lA = lds + 8192 + buf * 4096;
    const char* bB = lds + 16384 + buf * 16384;
#pragma unroll
    for (int ks = 0; ks < 2; ++ks) {
      bf16x8 ah[2], al[2], b[2];
#pragma unroll
      for (int mf = 0; mf < 2; ++mf) {
        int mloc = mf * 16 + (lane & 15);
        int ka = (ks * 64 + (lane >> 4) * 16) ^ ((mloc & 7) << 4);
        ah[mf] = *(const bf16x8*)(hA + mloc * 128 + ka);
        al[mf] = *(const bf16x8*)(lA + mloc * 128 + ka);
      }
#pragma unroll
      for (int nf = 0; nf < 2; ++nf) {
        int nloc = wn * 32 + nf * 16 + (lane & 15);
        int kb = (ks * 64 + (lane >> 4) * 16) ^ ((nloc & 7) << 4);
        b[nf] = *(const bf16x8*)(bB + nloc * 128 + kb);
      }
#pragma unroll
      for (int mf = 0; mf < 2; ++mf)
#pragma unroll
        for (int nf = 0; nf < 2; ++nf) {
          acc[mf][nf] = __builtin_amdgcn_mfma_f32_16x16x32_bf16(ah[mf], b[nf], acc[mf][nf], 0, 0, 0);
          acc[mf][nf] = __builtin_amdgcn_mfma_f32_16x16x32_bf16(al[mf], b[nf], acc[mf][nf], 0, 0, 0);
        }
    }
    if (kt < 15) writeA(buf ^ 1);
    __builtin_amdgcn_sched_barrier(0);
    asm volatile("s_waitcnt lgkmcnt(0)" ::: "memory");
    __builtin_amdgcn_s_barrier();
  }
#pragma unroll
  for (int mf = 0; mf < 2; ++mf)
#pragma unroll
    for (int nf = 0; nf < 2; ++nf)
#pragma unroll
      for (int r = 0; r < 4; ++r) {
        int row = mb * 32 + mf * 16 + (lane >> 4) * 4 + r;
        int col = nb * 128 + wn * 32 + nf * 16 + (lane & 15);
        float val = acc[mf][nf][r];
        unsigned short hi, lo;
        split2(val, hi, lo);
        Abuf[(size_t)row * 1280 + col] = hi;
        Abuf[(size_t)row * 1280 + 256 + col] = lo;
      }
}

// ---------------- G2: zero-skip T = h_g @ Bg, BM=64, N=192, K=256, 2-phase
__global__ __launch_bounds__(256) void g2_t(const float* __restrict__ h,
                                            const unsigned short* __restrict__ Bg,
                                            unsigned short* __restrict__ Abuf) {
  __shared__ char lds[65536];
  const int tid = threadIdx.x, lane = tid & 63, wid = tid >> 6;
  const int mb = blockIdx.x, g = blockIdx.y;
  const int wm = wid >> 1, wn = wid & 1;
  f32x4 acc[2][6] = {};
  float4 hr[4];
  const int r0 = tid >> 4, f4c = tid & 15;
  const float* hbase = h + (size_t)(mb * 64) * 1024 + g * 256 + f4c * 4;

  auto loadH = [&](int kt) {
#pragma unroll
    for (int q = 0; q < 4; ++q)
      hr[q] = *(const float4*)(hbase + (size_t)(q * 16 + r0) * 1024 + kt * 64);
  };
  auto writeA = [&](int buf) {
#pragma unroll
    for (int q = 0; q < 4; ++q) {
      int row = q * 16 + r0;
      float4 v = hr[q];
      int ba = row * 128 + ((f4c * 8) ^ ((row & 7) << 4));
      *(uint2*)(lds + buf * 8192 + ba) =
          make_uint2(((unsigned)f2bf(v.y) << 16) | f2bf(v.x),
                     ((unsigned)f2bf(v.w) << 16) | f2bf(v.z));
    }
  };
  auto stageB = [&](int kt, int buf) {
#pragma unroll
    for (int it = 0; it < 6; ++it) {
      int nloc = it * 32 + wid * 8 + (lane >> 3);
      const char* src = (const char*)Bg + (size_t)(g * 192 + nloc) * 512 + kt * 128
                        + (((lane & 7) * 16) ^ ((nloc & 7) << 4));
      gload16(src, lds + 16384 + buf * 24576 + (it * 32 + wid * 8) * 128);
    }
  };

  loadH(0); stageB(0, 0); writeA(0);
  __syncthreads();
#pragma unroll
  for (int kt = 0; kt < 4; ++kt) {
    int buf = kt & 1;
    if (kt < 3) { loadH(kt + 1); stageB(kt + 1, buf ^ 1); }
    const char* cA = lds + buf * 8192;
    const char* cB = lds + 16384 + buf * 24576;
#pragma unroll
    for (int ks = 0; ks < 2; ++ks) {
      bf16x8 a[2], b[6];
#pragma unroll
      for (int mf = 0; mf < 2; ++mf) {
        int mloc = wm * 32 + mf * 16 + (lane & 15);
        int ka = (ks * 64 + (lane >> 4) * 16) ^ ((mloc & 7) << 4);
        a[mf] = *(const bf16x8*)(cA + mloc * 128 + ka);
      }
#pragma unroll
      for (int nf = 0; nf < 6; ++nf) {
        int nloc = wn * 96 + nf * 16 + (lane & 15);
        int kb = (ks * 64 + (lane >> 4) * 16) ^ ((nloc & 7) << 4);
        b[nf] = *(const bf16x8*)(cB + nloc * 128 + kb);
      }
#pragma unroll
      for (int mf = 0; mf < 2; ++mf)
#pragma unroll
        for (int nf = 0; nf < 6; ++nf)
          acc[mf][nf] = __builtin_amdgcn_mfma_f32_16x16x32_bf16(a[mf], b[nf], acc[mf][nf], 0, 0, 0);
    }
    if (kt < 3) writeA(buf ^ 1);
    __syncthreads();
  }
#pragma unroll
  for (int mf = 0; mf < 2; ++mf)
#pragma unroll
    for (int nf = 0; nf < 6; ++nf) {
      int n = wn * 96 + nf * 16 + (lane & 15);
      int jj = 0, rr = n;
#pragma unroll
      for (int s = 0; s < 3; ++s) {
        int w = (((g - jj) & 3) < 2) ? 64 : 32;
        if (rr >= w) { rr -= w; ++jj; }
      }
      int v = (g - jj) & 3;
      int offv = (v < 2) ? (v << 6) : (64 + (v << 5));
      int col = 512 + jj * 192 + offv + rr;
#pragma unroll
      for (int r = 0; r < 4; ++r) {
        int row = mb * 64 + wm * 32 + mf * 16 + (lane >> 4) * 4 + r;
        Abuf[(size_t)row * 1280 + col] = f2bf(acc[mf][nf][r]);
      }
    }
}

// ---------------- G3: fused GEMM + GRU epilogue, fat-accumulator geometry
// Block: BM=128, 64 cols of group j, 4 waves (2M x 2N)
// Wave: M64 x (4 planes x 32 cols) -> acc[4][8] = 128 VGPR
// LDS: A 2x16KB @0, B 2x24KB @32768 (80 KiB); counted vmcnt(10)
__global__ __launch_bounds__(256) void g3_main(const unsigned short* __restrict__ Abuf,
                                               const unsigned short* __restrict__ Btp,
                                               const float* __restrict__ h,
                                               const float* __restrict__ bias_r,
                                               const float* __restrict__ bias_g,
                                               const float* __restrict__ bias_u,
                                               float* __restrict__ out) {
  __shared__ char lds[81920];
  const int tid = threadIdx.x, lane = tid & 63, wid = tid >> 6;
  const int mb = blockIdx.x, cb = blockIdx.y, j = blockIdx.z;
  const int wm = wid >> 1, wn = wid & 1;
  f32x4 acc[4][8] = {};

  const char* AbufB = (const char*)Abuf + (size_t)mb * 128 * 2560;
  const char* BtpJ  = (const char*)Btp + (size_t)j * 1081344;
  int thrA[4], dstA[4], thrB[6], dstB[6];
#pragma unroll
  for (int it = 0; it < 4; ++it) {
    int mloc = wid * 32 + it * 8 + (lane >> 3);
    thrA[it] = mloc * 2560 + (((lane & 7) * 16) ^ ((mloc & 7) << 4));
    dstA[it] = (wid * 32 + it * 8) * 128;
  }
#pragma unroll
  for (int it = 0; it < 6; ++it) {
    int rB = it * 32 + wid * 8 + (lane >> 3);
    thrB[it] = rB * 128 + (((lane & 7) * 16) ^ ((rB & 7) << 4));
    dstB[it] = (it * 32 + wid * 8) * 128;
  }
  // hoisted ds_read byte-offsets
  int pA[4][2], pB[3][2][2];
#pragma unroll
  for (int mf = 0; mf < 4; ++mf) {
    int mloc = wm * 64 + mf * 16 + (lane & 15);
#pragma unroll
    for (int ks = 0; ks < 2; ++ks)
      pA[mf][ks] = mloc * 128 + ((ks * 64 + (lane >> 4) * 16) ^ ((mloc & 7) << 4));
  }
#pragma unroll
  for (int q = 0; q < 3; ++q)
#pragma unroll
    for (int cf = 0; cf < 2; ++cf) {
      int rB = ((wn * 2 + cf) * 3 + q) * 16 + (lane & 15);
#pragma unroll
      for (int ks = 0; ks < 2; ++ks)
        pB[q][cf][ks] = 32768 + rB * 128 + ((ks * 64 + (lane >> 4) * 16) ^ ((rB & 7) << 4));
    }

  auto stage = [&](int kt, int buf) {
    int colb2 = (kt < 8) ? kt * 128 : (1024 + j * 384 + (kt - 8) * 128);
#pragma unroll
    for (int it = 0; it < 4; ++it)
      gload16(AbufB + colb2 + thrA[it], lds + buf * 16384 + dstA[it]);
    const char* bsrc = BtpJ + (size_t)(kt * 16 + cb * 4) * 6144;
#pragma unroll
    for (int it = 0; it < 6; ++it)
      gload16(bsrc + thrB[it], lds + buf * 24576 + 32768 + dstB[it]);
  };

  stage(0, 0);
#pragma unroll
  for (int kt = 0; kt < 11; ++kt) {
    const int buf = kt & 1;
    if (kt < 10) {
      stage(kt + 1, buf ^ 1);
      asm volatile("s_waitcnt vmcnt(10)" ::: "memory");
    } else {
      asm volatile("s_waitcnt vmcnt(0)" ::: "memory");
    }
    __builtin_amdgcn_s_barrier();
    __builtin_amdgcn_sched_barrier(0);
    __builtin_amdgcn_s_setprio(1);
#pragma unroll
    for (int ks = 0; ks < 2; ++ks) {
      bf16x8 a[4];
#pragma unroll
      for (int mf = 0; mf < 4; ++mf)
        a[mf] = *(const bf16x8*)(lds + buf * 16384 + pA[mf][ks]);
#pragma unroll
      for (int q = 0; q < 3; ++q) {
        const int p = (kt < 8) ? q : ((q == 2) ? 3 : q);
#pragma unroll
        for (int cf = 0; cf < 2; ++cf) {
          bf16x8 b = *(const bf16x8*)(lds + buf * 24576 + pB[q][cf][ks]);
#pragma unroll
          for (int mf = 0; mf < 4; ++mf)
            acc[mf][p * 2 + cf] =
                __builtin_amdgcn_mfma_f32_16x16x32_bf16(a[mf], b, acc[mf][p * 2 + cf], 0, 0, 0);
        }
      }
    }
    __builtin_amdgcn_s_setprio(0);
    __builtin_amdgcn_sched_barrier(0);
    asm volatile("s_waitcnt lgkmcnt(0)" ::: "memory");
    __builtin_amdgcn_s_barrier();
  }
  // fused GRU epilogue
#pragma unroll
  for (int cf = 0; cf < 2; ++cf) {
    int cg = j * 256 + cb * 64 + wn * 32 + cf * 16 + (lane & 15);
    float br = bias_r[cg], bg = bias_g[cg], bu = bias_u[cg];
#pragma unroll
    for (int mf = 0; mf < 4; ++mf)
#pragma unroll
      for (int r = 0; r < 4; ++r) {
        int row = mb * 128 + wm * 64 + mf * 16 + (lane >> 4) * 4 + r;
        float p0 = acc[mf][0 + cf][r], p1 = acc[mf][2 + cf][r];
        float p2 = acc[mf][4 + cf][r], p3 = acc[mf][6 + cf][r];
        float rr = sigm(p0 + br);
        float zz = sigm(p1 + bg);
        float ct = tanha(p2 + rr * p3 + bu);
        float hv = h[(size_t)row * 1024 + cg];
        out[(size_t)row * 1024 + cg] = zz * hv + (1.0f - zz) * ct;
      }
  }
}

extern "C" void kernel_launch(void* const* d_in, const int* in_sizes, int n_in,
                              void* d_out, int out_size, void* d_ws, size_t ws_size,
                              hipStream_t stream) {
  const float* x   = (const float*)d_in[0];
  const float* h   = (const float*)d_in[1];
  const float* W   = (const float*)d_in[2];
  const float* W1  = (const float*)d_in[3];
  const float* W2  = (const float*)d_in[4];
  const float* W3  = (const float*)d_in[5];
  const float* U   = (const float*)d_in[6];
  const float* U1  = (const float*)d_in[7];
  const float* U2  = (const float*)d_in[8];
  const float* U3  = (const float*)d_in[9];
  const float* UU   = (const float*)d_in[10];
  const float* UU1  = (const float*)d_in[11];
  const float* UU2  = (const float*)d_in[12];
  const float* UU3  = (const float*)d_in[13];
  const float* UUU   = (const float*)d_in[14];
  const float* UUU1  = (const float*)d_in[15];
  const float* UUU2  = (const float*)d_in[16];
  const float* UUU3  = (const float*)d_in[17];
  const float* UUUU   = (const float*)d_in[18];
  const float* UUUU1  = (const float*)d_in[19];
  const float* UUUU2  = (const float*)d_in[20];
  const float* UUUU3  = (const float*)d_in[21];
  const float* bias_r = (const float*)d_in[22];
  const float* bias_g = (const float*)d_in[23];
  const float* bias_u = (const float*)d_in[24];

  char* ws = (char*)d_ws;
  unsigned short* Abuf = (unsigned short*)(ws);              // 8192x1280 bf16, row-major
  unsigned short* Wt   = (unsigned short*)(ws + 20971520);   // 256x1024 bf16
  unsigned short* Bg   = (unsigned short*)(ws + 21495808);   // 4x192x256 bf16
  unsigned short* Btp  = (unsigned short*)(ws + 21889024);   // 4x11x16x48x64 bf16
  float* out = (float*)d_out;

  s123<<<10240, 256, 0, stream>>>(W, U, UU, UUU, UUUU,
                                  W1, W2, W3, U1, U2, U3, UU1, UU2, UU3,
                                  UUU1, UUU2, UUU3, UUUU1, UUUU2, UUUU3,
                                  Wt, Bg, Btp);
  g1_xw<<<dim3(256, 2), 256, 0, stream>>>(x, Wt, Abuf);
  g2_t<<<dim3(128, 4), 256, 0, stream>>>(h, Bg, Abuf);
  g3_main<<<dim3(64, 4, 4), 256, 0, stream>>>(Abuf, Btp, h, bias_r, bias_g, bias_u, out);
}